// Round 7
// baseline (384.619 us; speedup 1.0000x reference)
//
#include <hip/hip_runtime.h>
#include <hip/hip_bf16.h>

// SocialGNN: 2-layer GCN, N=100000 nodes, E=1600000 edges (+ self loops),
// feat 256 -> 128 (relu) -> 16.
//
// R6 (resubmitted R7 -- broker timeout, never benched): gemm1 rewritten
// LDS-free (direct per-lane A loads from X + in-register bf16 convert; B
// straight from L1-hot W1t; zero barriers). agg2 reworked to 4 lanes/node
// (uint2 loads, wave=16 nodes, uniform max-deg loop). agg1 reverted to
// 4-unroll (R5's 8-unroll cost VGPRs, gained nothing).
// History: R2 -- never funnel E atomics into <1K addresses (~210ns each).
// R4 -- bf16 intermediates halve gather traffic; error attenuated by
// dinv~0.24 twice per layer (absmax 2e-3 vs 9e-3 threshold). R5 -- agg1 is
// request-rate/latency bound at ~74us, more unroll doesn't help.

typedef __attribute__((ext_vector_type(8))) short short8;
typedef __attribute__((ext_vector_type(4))) float f32x4;

__device__ inline unsigned short f2bf(float f) {
    __hip_bfloat16 h = __float2bfloat16(f);
    return *(unsigned short*)&h;
}
__device__ inline float bf2f(unsigned short u) {
    unsigned int v = ((unsigned int)u) << 16;
    return *(float*)&v;
}

#define N_FEAT_IN 256
#define NBUCK 1024     // dst>>7; used buckets = ceil(n/128) = 782
#define NBINBLK 256    // partition blocks; bbc is [NBUCK][NBINBLK]

// ---------------- partition pass 1: per-(block,bucket) LDS histogram ----------------
__global__ __launch_bounds__(256) void k_bhist(const int* __restrict__ dst,
                                               int* __restrict__ bbc, int E, int chunk) {
    __shared__ int lcnt[NBUCK];
    for (int i = threadIdx.x; i < NBUCK; i += 256) lcnt[i] = 0;
    __syncthreads();
    int start = blockIdx.x * chunk;
    int end = min(start + chunk, E);
    for (int e = start + threadIdx.x; e < end; e += 256)
        atomicAdd(&lcnt[dst[e] >> 7], 1);
    __syncthreads();
    for (int i = threadIdx.x; i < NBUCK; i += 256)
        bbc[i * NBINBLK + blockIdx.x] = lcnt[i];
}

// ---- partition pass 2: per-bucket local exclusive scan across blocks + totals ----
__global__ __launch_bounds__(256) void k_bexscan(int* __restrict__ bbc,
                                                 int* __restrict__ btot) {
    __shared__ int ts[NBINBLK];
    int bucket = blockIdx.x;
    int t = threadIdx.x;
    int v = bbc[bucket * NBINBLK + t];
    ts[t] = v; __syncthreads();
    for (int off = 1; off < NBINBLK; off <<= 1) {
        int x = (t >= off) ? ts[t - off] : 0;
        __syncthreads();
        ts[t] += x;
        __syncthreads();
    }
    bbc[bucket * NBINBLK + t] = ts[t] - v;   // local exclusive (no base yet)
    if (t == NBINBLK - 1) btot[bucket] = ts[t];
}

// ---------------- bucket-total exclusive scan -> bucket bases ----------------
__global__ __launch_bounds__(1024) void k_bscan(const int* __restrict__ btot,
                                                int* __restrict__ bbase) {
    __shared__ int ts[NBUCK];
    int t = threadIdx.x;
    int v = btot[t];
    ts[t] = v; __syncthreads();
    for (int off = 1; off < NBUCK; off <<= 1) {
        int x = (t >= off) ? ts[t - off] : 0;
        __syncthreads();
        ts[t] += x;
        __syncthreads();
    }
    bbase[t] = ts[t] - v;  // exclusive
}

// ---------------- partition pass 3: binned write (24-bit packed) ----------------
// packed edge: bits 0-16 src (n<2^17), bits 17-23 dst&127.
__global__ __launch_bounds__(256) void k_bin2(const int* __restrict__ src,
                                              const int* __restrict__ dst,
                                              const int* __restrict__ bbc,
                                              const int* __restrict__ bbase,
                                              int* __restrict__ ebuf, int E, int chunk) {
    __shared__ int lcur[NBUCK];
    for (int i = threadIdx.x; i < NBUCK; i += 256)
        lcur[i] = bbc[i * NBINBLK + blockIdx.x] + bbase[i];
    __syncthreads();
    int start = blockIdx.x * chunk;
    int end = min(start + chunk, E);
    for (int e = start + threadIdx.x; e < end; e += 256) {
        int s = src[e], d = dst[e];
        int pos = atomicAdd(&lcur[d >> 7], 1);  // LDS atomic
        ebuf[pos] = s | ((d & 127) << 17);
    }
}

// ---- per-bucket counting sort: ebuf window -> csr; also row_ptr, dinv ----
__global__ __launch_bounds__(256) void k_sortb(const int* __restrict__ ebuf,
                                               const int* __restrict__ bbase,
                                               int* __restrict__ row_ptr,
                                               float* __restrict__ dinv,
                                               int* __restrict__ csr, int n, int E) {
    __shared__ int lcnt[128];
    __shared__ int lcur[128];
    int b = blockIdx.x;
    int node0 = b << 7;
    int nodes = min(128, n - node0);
    int t = threadIdx.x;
    int s_start = bbase[b];
    int s_end = bbase[b + 1];
    if (t < 128) lcnt[t] = 0;
    __syncthreads();
    for (int e = s_start + t; e < s_end; e += 256)
        atomicAdd(&lcnt[(ebuf[e] >> 17) & 127], 1);
    __syncthreads();
    int deg = (t < 128) ? lcnt[t] : 0;
    if (t < 128) lcur[t] = deg;
    __syncthreads();
    for (int off = 1; off < 128; off <<= 1) {
        int x = 0;
        if (t < 128 && t >= off) x = lcur[t - off];
        __syncthreads();
        if (t < 128) lcur[t] += x;
        __syncthreads();
    }
    if (t < 128) {
        int excl = s_start + lcur[t] - deg;
        if (t < nodes) {
            row_ptr[node0 + t] = excl;
            dinv[node0 + t] = rsqrtf((float)deg + 1.0f);  // +1 self-loop
        }
        lcur[t] = excl;  // write cursor
    }
    if (b == 0 && t == 0) row_ptr[n] = E;
    __syncthreads();
    for (int e = s_start + t; e < s_end; e += 256) {
        int p = ebuf[e];
        int pos = atomicAdd(&lcur[(p >> 17) & 127], 1);  // LDS atomic
        csr[pos] = p & 0x1FFFF;
    }
}

// ---------------- W1 [256][128] f32 -> W1t [128][256] bf16 ----------------
__global__ void k_prep(const float* __restrict__ W1, unsigned short* __restrict__ W1t) {
    int nn = blockIdx.x;          // 0..127
    int k = threadIdx.x;          // 0..255
    W1t[nn * 256 + k] = f2bf(W1[k * 128 + nn]);
}

// ---------------- GEMM1 (MFMA, LDS-free): X[M,256]f32 @ W1t -> h1s bf16, *dinv ------
// 4 waves/block; wave wv covers rows [block*64 + 16wv, +16). A fragment loaded
// directly per lane (A[m=l15][k=hq*8+j] -> 32 B from X row), converted to bf16
// in-register. B fragments read from W1t (64 KB, L1-hot). No LDS, no barriers.
__global__ __launch_bounds__(256) void k_gemm1(const float* __restrict__ X,
                                               const unsigned short* __restrict__ W1t,
                                               const float* __restrict__ dinv,
                                               unsigned short* __restrict__ h1s, int M) {
    const int tid = threadIdx.x;
    const int wv = tid >> 6;
    const int lane = tid & 63;
    const int hq = lane >> 4;       // quad 0..3
    const int l15 = lane & 15;
    const int block_row = blockIdx.x * 64;

    int arow = block_row + wv * 16 + l15;
    if (arow >= M) arow = M - 1;                       // clamp; stores masked
    const float* xp = X + (size_t)arow * 256 + hq * 8;

    f32x4 acc[8];
#pragma unroll
    for (int c = 0; c < 8; ++c) acc[c] = (f32x4){0.f, 0.f, 0.f, 0.f};

#pragma unroll
    for (int kq = 0; kq < 8; ++kq) {                   // k0 = 32*kq
        float4 a0 = *(const float4*)(xp + 32 * kq);
        float4 a1 = *(const float4*)(xp + 32 * kq + 4);
        short8 a;
        a[0] = (short)f2bf(a0.x); a[1] = (short)f2bf(a0.y);
        a[2] = (short)f2bf(a0.z); a[3] = (short)f2bf(a0.w);
        a[4] = (short)f2bf(a1.x); a[5] = (short)f2bf(a1.y);
        a[6] = (short)f2bf(a1.z); a[7] = (short)f2bf(a1.w);
#pragma unroll
        for (int c = 0; c < 8; ++c) {
            short8 b = *(const short8*)(W1t + (size_t)(c * 16 + l15) * 256 + 32 * kq + hq * 8);
            acc[c] = __builtin_amdgcn_mfma_f32_16x16x32_bf16(a, b, acc[c], 0, 0, 0);
        }
    }
    // D: row = 16wv + hq*4 + r, col = c*16 + l15
#pragma unroll
    for (int r = 0; r < 4; ++r) {
        int row = block_row + 16 * wv + hq * 4 + r;
        if (row < M) {
            float dv = dinv[row];
#pragma unroll
            for (int c = 0; c < 8; ++c) {
                int col = c * 16 + l15;
                h1s[(size_t)row * 128 + col] = f2bf(acc[c][r] * dv);
            }
        }
    }
}

// ---------------- agg1: one wave per node, 128 bf16 feats (bf16x2/lane) ----------------
__global__ __launch_bounds__(256) void k_agg1(const unsigned short* __restrict__ h1s,
                                              const int* __restrict__ rp,
                                              const int* __restrict__ csr,
                                              const float* __restrict__ dinv,
                                              const float* __restrict__ b1,
                                              unsigned short* __restrict__ tbuf, int n) {
    int w = (blockIdx.x * 256 + threadIdx.x) >> 6;  // global wave = node
    int lane = threadIdx.x & 63;
    if (w >= n) return;
    const unsigned int* hv = (const unsigned int*)h1s;  // packed bf16x2
    unsigned int us = hv[((unsigned)w << 6) + lane];    // self (already *dinv)
    float ax = __uint_as_float(us << 16);
    float ay = __uint_as_float(us & 0xffff0000u);
    int start = rp[w], end = rp[w + 1];
    int e = start;
    for (; e + 4 <= end; e += 4) {
        unsigned int u0 = hv[((unsigned)csr[e + 0] << 6) + lane];
        unsigned int u1 = hv[((unsigned)csr[e + 1] << 6) + lane];
        unsigned int u2 = hv[((unsigned)csr[e + 2] << 6) + lane];
        unsigned int u3 = hv[((unsigned)csr[e + 3] << 6) + lane];
        ax += (__uint_as_float(u0 << 16) + __uint_as_float(u1 << 16)) +
              (__uint_as_float(u2 << 16) + __uint_as_float(u3 << 16));
        ay += (__uint_as_float(u0 & 0xffff0000u) + __uint_as_float(u1 & 0xffff0000u)) +
              (__uint_as_float(u2 & 0xffff0000u) + __uint_as_float(u3 & 0xffff0000u));
    }
    for (; e < end; ++e) {
        unsigned int u = hv[((unsigned)csr[e] << 6) + lane];
        ax += __uint_as_float(u << 16);
        ay += __uint_as_float(u & 0xffff0000u);
    }
    float dv = dinv[w];
    float2 bb = ((const float2*)b1)[lane];
    float tx = fmaxf(dv * ax + bb.x, 0.0f);
    float ty = fmaxf(dv * ay + bb.y, 0.0f);
    unsigned int packed = (unsigned int)f2bf(tx) | ((unsigned int)f2bf(ty) << 16);
    ((unsigned int*)tbuf)[((unsigned)w << 6) + lane] = packed;
}

// ---------------- GEMM2: tbuf[n,128]bf16 @ W2[128,16]f32 -> h2s bf16, *dinv ----------
__global__ __launch_bounds__(256) void k_gemm2(const unsigned short* __restrict__ tbuf,
                                               const float* __restrict__ W2,
                                               const float* __restrict__ dinv,
                                               unsigned short* __restrict__ h2s, int n) {
    __shared__ float w2s[128 * 16];
    for (int i = threadIdx.x; i < 2048; i += 256) w2s[i] = W2[i];
    __syncthreads();
    int gid = blockIdx.x * 256 + threadIdx.x;
    int node = gid >> 4;
    int o = gid & 15;
    if (node >= n) return;
    const uint4* tv = (const uint4*)(tbuf + (size_t)node * 128);  // 16 x uint4
    float acc = 0.0f;
#pragma unroll
    for (int i = 0; i < 16; ++i) {
        uint4 u = tv[i];
        int k = i * 8;
        acc += __uint_as_float(u.x << 16) * w2s[(k + 0) * 16 + o];
        acc += __uint_as_float(u.x & 0xffff0000u) * w2s[(k + 1) * 16 + o];
        acc += __uint_as_float(u.y << 16) * w2s[(k + 2) * 16 + o];
        acc += __uint_as_float(u.y & 0xffff0000u) * w2s[(k + 3) * 16 + o];
        acc += __uint_as_float(u.z << 16) * w2s[(k + 4) * 16 + o];
        acc += __uint_as_float(u.z & 0xffff0000u) * w2s[(k + 5) * 16 + o];
        acc += __uint_as_float(u.w << 16) * w2s[(k + 6) * 16 + o];
        acc += __uint_as_float(u.w & 0xffff0000u) * w2s[(k + 7) * 16 + o];
    }
    h2s[(size_t)node * 16 + o] = f2bf(acc * dinv[node]);
}

// ---------------- agg2: 4 lanes/node, uint2 (4 bf16 feats) per lane ----------------
// lane = slot*4 + q; slot in [0,16): 16 nodes per wave. Wave loops to max
// degree among its 16 nodes, per-lane predicated (clamped csr index).
__global__ __launch_bounds__(256) void k_agg2(const unsigned short* __restrict__ h2s,
                                              const int* __restrict__ rp,
                                              const int* __restrict__ csr,
                                              const float* __restrict__ dinv,
                                              const float* __restrict__ b2,
                                              float* __restrict__ out, int n) {
    int wid = (blockIdx.x * 256 + threadIdx.x) >> 6;
    int lane = threadIdx.x & 63;
    int slot = lane >> 2;
    int q = lane & 3;
    int node = wid * 16 + slot;
    bool valid = node < n;
    int nodec = valid ? node : n - 1;
    int start = rp[nodec];
    int deg = rp[nodec + 1] - start;
    // wave max degree
    int mx = deg;
#pragma unroll
    for (int off = 4; off < 64; off <<= 1) mx = max(mx, __shfl_xor(mx, off));
    // self term (h2s already *dinv)
    uint2 us = *(const uint2*)(h2s + ((unsigned)nodec << 4) + q * 4);
    float a0 = bf2f((unsigned short)(us.x & 0xffff));
    float a1 = bf2f((unsigned short)(us.x >> 16));
    float a2 = bf2f((unsigned short)(us.y & 0xffff));
    float a3 = bf2f((unsigned short)(us.y >> 16));
    int clampi = deg > 0 ? deg - 1 : 0;
    int e = 0;
    for (; e + 2 <= mx; e += 2) {
        int s0 = csr[start + min(e, clampi)];
        int s1 = csr[start + min(e + 1, clampi)];
        uint2 u0 = *(const uint2*)(h2s + ((unsigned)s0 << 4) + q * 4);
        uint2 u1 = *(const uint2*)(h2s + ((unsigned)s1 << 4) + q * 4);
        if (e < deg) {
            a0 += bf2f((unsigned short)(u0.x & 0xffff));
            a1 += bf2f((unsigned short)(u0.x >> 16));
            a2 += bf2f((unsigned short)(u0.y & 0xffff));
            a3 += bf2f((unsigned short)(u0.y >> 16));
        }
        if (e + 1 < deg) {
            a0 += bf2f((unsigned short)(u1.x & 0xffff));
            a1 += bf2f((unsigned short)(u1.x >> 16));
            a2 += bf2f((unsigned short)(u1.y & 0xffff));
            a3 += bf2f((unsigned short)(u1.y >> 16));
        }
    }
    if (e < mx && e < deg) {
        int s = csr[start + e];
        uint2 u = *(const uint2*)(h2s + ((unsigned)s << 4) + q * 4);
        a0 += bf2f((unsigned short)(u.x & 0xffff));
        a1 += bf2f((unsigned short)(u.x >> 16));
        a2 += bf2f((unsigned short)(u.y & 0xffff));
        a3 += bf2f((unsigned short)(u.y >> 16));
    }
    if (valid) {
        float dv = dinv[node];
        float4 bb = *(const float4*)(b2 + q * 4);
        float4 o4 = make_float4(dv * a0 + bb.x, dv * a1 + bb.y,
                                dv * a2 + bb.z, dv * a3 + bb.w);
        *(float4*)(out + ((unsigned)node << 4) + q * 4) = o4;
    }
}

extern "C" void kernel_launch(void* const* d_in, const int* in_sizes, int n_in,
                              void* d_out, int out_size, void* d_ws, size_t ws_size,
                              hipStream_t stream) {
    const float* X  = (const float*)d_in[0];
    const int*   ei = (const int*)d_in[1];
    const float* W1 = (const float*)d_in[2];
    const float* b1 = (const float*)d_in[3];
    const float* W2 = (const float*)d_in[4];
    const float* b2 = (const float*)d_in[5];
    float* out = (float*)d_out;

    const int n = in_sizes[0] / N_FEAT_IN;   // 100000
    const int E = in_sizes[1] / 2;           // 1600000
    const int* src = ei;
    const int* dst = ei + E;

    char* ws = (char*)d_ws;
    size_t off = 0;
    auto alloc = [&](size_t bytes) -> char* {
        char* p = ws + off;
        off = (off + bytes + 255) & ~(size_t)255;
        return p;
    };
    float*          dinv    = (float*)alloc((size_t)n * 4);
    int*            row_ptr = (int*)alloc((size_t)(n + 1) * 4);
    int*            bbc     = (int*)alloc((size_t)NBUCK * NBINBLK * 4);  // 1 MB
    int*            btot    = (int*)alloc(NBUCK * 4);
    int*            bbase   = (int*)alloc((NBUCK + 1) * 4);
    int*            csr     = (int*)alloc((size_t)E * 4);
    int*            ebuf    = (int*)alloc((size_t)E * 4);                // 6.4 MB packed
    unsigned short* W1t     = (unsigned short*)alloc(128 * 256 * 2);     // 64 KB
    unsigned short* h1s     = (unsigned short*)alloc((size_t)n * 128 * 2);
    unsigned short* tbuf    = (unsigned short*)alloc((size_t)n * 128 * 2);
    unsigned short* h2s     = (unsigned short*)alloc((size_t)n * 16 * 2);
    (void)ws_size;

    const int NBK = (n + 127) / 128;         // 782 used buckets
    const int chunk = (E + NBINBLK - 1) / NBINBLK;

    k_bhist<<<NBINBLK, 256, 0, stream>>>(dst, bbc, E, chunk);
    k_bexscan<<<NBUCK, 256, 0, stream>>>(bbc, btot);
    k_bscan<<<1, NBUCK, 0, stream>>>(btot, bbase);
    k_bin2<<<NBINBLK, 256, 0, stream>>>(src, dst, bbc, bbase, ebuf, E, chunk);
    k_sortb<<<NBK, 256, 0, stream>>>(ebuf, bbase, row_ptr, dinv, csr, n, E);

    k_prep<<<128, 256, 0, stream>>>(W1, W1t);
    k_gemm1<<<(n + 63) / 64, 256, 0, stream>>>(X, W1t, dinv, h1s, n);
    k_agg1<<<(n + 3) / 4, 256, 0, stream>>>(h1s, row_ptr, csr, dinv, b1, tbuf, n);
    k_gemm2<<<((size_t)n * 16 + 255) / 256, 256, 0, stream>>>(tbuf, W2, dinv, h2s, n);
    k_agg2<<<(n + 63) / 64, 256, 0, stream>>>(h2s, row_ptr, csr, dinv, b2, out, n);
}

// Round 8
// 351.868 us; speedup vs baseline: 1.0931x; 1.0931x over previous
//
#include <hip/hip_runtime.h>
#include <hip/hip_bf16.h>

// SocialGNN: 2-layer GCN, N=100000 nodes, E=1600000 edges (+ self loops),
// feat 256 -> 128 (relu) -> 16.
//
// R8: revert gemm1 to the R5 LDS/MFMA version (R7's LDS-free variant was
// 85us: 64 dependent L2-hit B-loads per wave, MfmaUtil 2.8% -- per-wave-
// redundant operand streams belong in LDS). agg1 reworked to 2 nodes/wave
// (32 lanes x uint2 per row) to double gather-row MLP.
// History: R2 -- never funnel E atomics into <1K addresses (~210ns each).
// R4 -- bf16 intermediates halve gather traffic; error attenuated by
// dinv~0.24 twice per layer (absmax 2e-3 vs 9e-3 threshold). R5 -- agg1
// plateau ~74us at 190MB FETCH; more unroll alone doesn't help. R7 -- LDS-free
// MFMA operand streaming from global is a 2x regression.

typedef __attribute__((ext_vector_type(8))) short short8;
typedef __attribute__((ext_vector_type(4))) float f32x4;

__device__ inline unsigned short f2bf(float f) {
    __hip_bfloat16 h = __float2bfloat16(f);
    return *(unsigned short*)&h;
}
__device__ inline float bf2f(unsigned short u) {
    unsigned int v = ((unsigned int)u) << 16;
    return *(float*)&v;
}

#define N_FEAT_IN 256
#define NBUCK 1024     // dst>>7; used buckets = ceil(n/128) = 782
#define NBINBLK 256    // partition blocks; bbc is [NBUCK][NBINBLK]

// ---------------- partition pass 1: per-(block,bucket) LDS histogram ----------------
__global__ __launch_bounds__(256) void k_bhist(const int* __restrict__ dst,
                                               int* __restrict__ bbc, int E, int chunk) {
    __shared__ int lcnt[NBUCK];
    for (int i = threadIdx.x; i < NBUCK; i += 256) lcnt[i] = 0;
    __syncthreads();
    int start = blockIdx.x * chunk;
    int end = min(start + chunk, E);
    for (int e = start + threadIdx.x; e < end; e += 256)
        atomicAdd(&lcnt[dst[e] >> 7], 1);
    __syncthreads();
    for (int i = threadIdx.x; i < NBUCK; i += 256)
        bbc[i * NBINBLK + blockIdx.x] = lcnt[i];
}

// ---- partition pass 2: per-bucket local exclusive scan across blocks + totals ----
__global__ __launch_bounds__(256) void k_bexscan(int* __restrict__ bbc,
                                                 int* __restrict__ btot) {
    __shared__ int ts[NBINBLK];
    int bucket = blockIdx.x;
    int t = threadIdx.x;
    int v = bbc[bucket * NBINBLK + t];
    ts[t] = v; __syncthreads();
    for (int off = 1; off < NBINBLK; off <<= 1) {
        int x = (t >= off) ? ts[t - off] : 0;
        __syncthreads();
        ts[t] += x;
        __syncthreads();
    }
    bbc[bucket * NBINBLK + t] = ts[t] - v;   // local exclusive (no base yet)
    if (t == NBINBLK - 1) btot[bucket] = ts[t];
}

// ---------------- bucket-total exclusive scan -> bucket bases ----------------
__global__ __launch_bounds__(1024) void k_bscan(const int* __restrict__ btot,
                                                int* __restrict__ bbase) {
    __shared__ int ts[NBUCK];
    int t = threadIdx.x;
    int v = btot[t];
    ts[t] = v; __syncthreads();
    for (int off = 1; off < NBUCK; off <<= 1) {
        int x = (t >= off) ? ts[t - off] : 0;
        __syncthreads();
        ts[t] += x;
        __syncthreads();
    }
    bbase[t] = ts[t] - v;  // exclusive
}

// ---------------- partition pass 3: binned write (24-bit packed) ----------------
// packed edge: bits 0-16 src (n<2^17), bits 17-23 dst&127.
__global__ __launch_bounds__(256) void k_bin2(const int* __restrict__ src,
                                              const int* __restrict__ dst,
                                              const int* __restrict__ bbc,
                                              const int* __restrict__ bbase,
                                              int* __restrict__ ebuf, int E, int chunk) {
    __shared__ int lcur[NBUCK];
    for (int i = threadIdx.x; i < NBUCK; i += 256)
        lcur[i] = bbc[i * NBINBLK + blockIdx.x] + bbase[i];
    __syncthreads();
    int start = blockIdx.x * chunk;
    int end = min(start + chunk, E);
    for (int e = start + threadIdx.x; e < end; e += 256) {
        int s = src[e], d = dst[e];
        int pos = atomicAdd(&lcur[d >> 7], 1);  // LDS atomic
        ebuf[pos] = s | ((d & 127) << 17);
    }
}

// ---- per-bucket counting sort: ebuf window -> csr; also row_ptr, dinv ----
__global__ __launch_bounds__(256) void k_sortb(const int* __restrict__ ebuf,
                                               const int* __restrict__ bbase,
                                               int* __restrict__ row_ptr,
                                               float* __restrict__ dinv,
                                               int* __restrict__ csr, int n, int E) {
    __shared__ int lcnt[128];
    __shared__ int lcur[128];
    int b = blockIdx.x;
    int node0 = b << 7;
    int nodes = min(128, n - node0);
    int t = threadIdx.x;
    int s_start = bbase[b];
    int s_end = bbase[b + 1];
    if (t < 128) lcnt[t] = 0;
    __syncthreads();
    for (int e = s_start + t; e < s_end; e += 256)
        atomicAdd(&lcnt[(ebuf[e] >> 17) & 127], 1);
    __syncthreads();
    int deg = (t < 128) ? lcnt[t] : 0;
    if (t < 128) lcur[t] = deg;
    __syncthreads();
    for (int off = 1; off < 128; off <<= 1) {
        int x = 0;
        if (t < 128 && t >= off) x = lcur[t - off];
        __syncthreads();
        if (t < 128) lcur[t] += x;
        __syncthreads();
    }
    if (t < 128) {
        int excl = s_start + lcur[t] - deg;
        if (t < nodes) {
            row_ptr[node0 + t] = excl;
            dinv[node0 + t] = rsqrtf((float)deg + 1.0f);  // +1 self-loop
        }
        lcur[t] = excl;  // write cursor
    }
    if (b == 0 && t == 0) row_ptr[n] = E;
    __syncthreads();
    for (int e = s_start + t; e < s_end; e += 256) {
        int p = ebuf[e];
        int pos = atomicAdd(&lcur[(p >> 17) & 127], 1);  // LDS atomic
        csr[pos] = p & 0x1FFFF;
    }
}

// ---------------- W1 [256][128] f32 -> W1t [128][256] bf16 ----------------
__global__ void k_prep(const float* __restrict__ W1, unsigned short* __restrict__ W1t) {
    int nn = blockIdx.x;          // 0..127
    int k = threadIdx.x;          // 0..255
    W1t[nn * 256 + k] = f2bf(W1[k * 128 + nn]);
}

// ---------------- GEMM1 (MFMA, LDS-staged): X[M,256]f32 @ W1t -> h1s bf16, *dinv ----
// R5 version (measured-good). block: 64 rows x 128 cols, 4 waves, BK=32.
__global__ __launch_bounds__(256) void k_gemm1(const float* __restrict__ X,
                                               const unsigned short* __restrict__ W1t,
                                               const float* __restrict__ dinv,
                                               unsigned short* __restrict__ h1s, int M) {
    __shared__ __align__(16) unsigned short As[64][40];   // [m][k], pad 40
    __shared__ __align__(16) unsigned short BsT[128][40]; // [n][k], pad 40
    const int tid = threadIdx.x;
    const int wv = tid >> 6;
    const int lane = tid & 63;
    const int hq = lane >> 4;       // quad 0..3
    const int l15 = lane & 15;
    const int block_row = blockIdx.x * 64;

    f32x4 acc[8];
#pragma unroll
    for (int c = 0; c < 8; ++c) acc[c] = (f32x4){0.f, 0.f, 0.f, 0.f};

    for (int k0 = 0; k0 < 256; k0 += 32) {
#pragma unroll
        for (int i = 0; i < 2; ++i) {
            int idx = tid + i * 256;
            int m = idx >> 3;
            int kq = idx & 7;
            int row = block_row + m;
            if (row >= M) row = M - 1;
            float4 v = *(const float4*)(X + (size_t)row * 256 + k0 + kq * 4);
            ushort4 bq;
            bq.x = f2bf(v.x); bq.y = f2bf(v.y); bq.z = f2bf(v.z); bq.w = f2bf(v.w);
            *(ushort4*)&As[m][kq * 4] = bq;
        }
#pragma unroll
        for (int i = 0; i < 2; ++i) {
            int idx = tid + i * 256;
            int nn = idx >> 2;
            int q = idx & 3;
            *(uint4*)&BsT[nn][q * 8] =
                *(const uint4*)(W1t + (size_t)nn * 256 + k0 + q * 8);
        }
        __syncthreads();
        short8 a = *(const short8*)&As[16 * wv + l15][hq * 8];
#pragma unroll
        for (int c = 0; c < 8; ++c) {
            short8 bb = *(const short8*)&BsT[c * 16 + l15][hq * 8];
            acc[c] = __builtin_amdgcn_mfma_f32_16x16x32_bf16(a, bb, acc[c], 0, 0, 0);
        }
        __syncthreads();
    }
#pragma unroll
    for (int r = 0; r < 4; ++r) {
        int row = block_row + 16 * wv + hq * 4 + r;
        if (row < M) {
            float dv = dinv[row];
#pragma unroll
            for (int c = 0; c < 8; ++c) {
                int col = c * 16 + l15;
                h1s[(size_t)row * 128 + col] = f2bf(acc[c][r] * dv);
            }
        }
    }
}

// ---------------- agg1: TWO nodes per wave (32 lanes x uint2 = 256B row) -------------
// half = lane>>5 picks the node; l = lane&31 owns 4 bf16 feats (uint2). One
// gather instruction covers two rows -> 2x row-MLP per wave, half the waves.
__global__ __launch_bounds__(256) void k_agg1(const unsigned short* __restrict__ h1s,
                                              const int* __restrict__ rp,
                                              const int* __restrict__ csr,
                                              const float* __restrict__ dinv,
                                              const float* __restrict__ b1,
                                              unsigned short* __restrict__ tbuf, int n) {
    int pr = (blockIdx.x * 256 + threadIdx.x) >> 6;  // wave id = node pair
    int lane = threadIdx.x & 63;
    int half = lane >> 5;
    int l = lane & 31;
    int node = pr * 2 + half;
    if (node >= n) return;
    const uint2* hv = (const uint2*)h1s;  // 32 uint2 per 128-feat row
    uint2 us = hv[((unsigned)node << 5) + l];  // self (already *dinv)
    float a0 = bf2f((unsigned short)(us.x & 0xffff));
    float a1 = bf2f((unsigned short)(us.x >> 16));
    float a2 = bf2f((unsigned short)(us.y & 0xffff));
    float a3 = bf2f((unsigned short)(us.y >> 16));
    int start = rp[node], end = rp[node + 1];
    int e = start;
    for (; e + 4 <= end; e += 4) {
        uint2 u0 = hv[((unsigned)csr[e + 0] << 5) + l];
        uint2 u1 = hv[((unsigned)csr[e + 1] << 5) + l];
        uint2 u2 = hv[((unsigned)csr[e + 2] << 5) + l];
        uint2 u3 = hv[((unsigned)csr[e + 3] << 5) + l];
        a0 += (bf2f((unsigned short)(u0.x & 0xffff)) + bf2f((unsigned short)(u1.x & 0xffff))) +
              (bf2f((unsigned short)(u2.x & 0xffff)) + bf2f((unsigned short)(u3.x & 0xffff)));
        a1 += (bf2f((unsigned short)(u0.x >> 16)) + bf2f((unsigned short)(u1.x >> 16))) +
              (bf2f((unsigned short)(u2.x >> 16)) + bf2f((unsigned short)(u3.x >> 16)));
        a2 += (bf2f((unsigned short)(u0.y & 0xffff)) + bf2f((unsigned short)(u1.y & 0xffff))) +
              (bf2f((unsigned short)(u2.y & 0xffff)) + bf2f((unsigned short)(u3.y & 0xffff)));
        a3 += (bf2f((unsigned short)(u0.y >> 16)) + bf2f((unsigned short)(u1.y >> 16))) +
              (bf2f((unsigned short)(u2.y >> 16)) + bf2f((unsigned short)(u3.y >> 16)));
    }
    for (; e < end; ++e) {
        uint2 u = hv[((unsigned)csr[e] << 5) + l];
        a0 += bf2f((unsigned short)(u.x & 0xffff));
        a1 += bf2f((unsigned short)(u.x >> 16));
        a2 += bf2f((unsigned short)(u.y & 0xffff));
        a3 += bf2f((unsigned short)(u.y >> 16));
    }
    float dv = dinv[node];
    float4 bb = ((const float4*)b1)[l];
    float t0 = fmaxf(dv * a0 + bb.x, 0.0f);
    float t1 = fmaxf(dv * a1 + bb.y, 0.0f);
    float t2 = fmaxf(dv * a2 + bb.z, 0.0f);
    float t3 = fmaxf(dv * a3 + bb.w, 0.0f);
    uint2 packed;
    packed.x = (unsigned int)f2bf(t0) | ((unsigned int)f2bf(t1) << 16);
    packed.y = (unsigned int)f2bf(t2) | ((unsigned int)f2bf(t3) << 16);
    ((uint2*)tbuf)[((unsigned)node << 5) + l] = packed;
}

// ---------------- GEMM2: tbuf[n,128]bf16 @ W2[128,16]f32 -> h2s bf16, *dinv ----------
__global__ __launch_bounds__(256) void k_gemm2(const unsigned short* __restrict__ tbuf,
                                               const float* __restrict__ W2,
                                               const float* __restrict__ dinv,
                                               unsigned short* __restrict__ h2s, int n) {
    __shared__ float w2s[128 * 16];
    for (int i = threadIdx.x; i < 2048; i += 256) w2s[i] = W2[i];
    __syncthreads();
    int gid = blockIdx.x * 256 + threadIdx.x;
    int node = gid >> 4;
    int o = gid & 15;
    if (node >= n) return;
    const uint4* tv = (const uint4*)(tbuf + (size_t)node * 128);  // 16 x uint4
    float acc = 0.0f;
#pragma unroll
    for (int i = 0; i < 16; ++i) {
        uint4 u = tv[i];
        int k = i * 8;
        acc += __uint_as_float(u.x << 16) * w2s[(k + 0) * 16 + o];
        acc += __uint_as_float(u.x & 0xffff0000u) * w2s[(k + 1) * 16 + o];
        acc += __uint_as_float(u.y << 16) * w2s[(k + 2) * 16 + o];
        acc += __uint_as_float(u.y & 0xffff0000u) * w2s[(k + 3) * 16 + o];
        acc += __uint_as_float(u.z << 16) * w2s[(k + 4) * 16 + o];
        acc += __uint_as_float(u.z & 0xffff0000u) * w2s[(k + 5) * 16 + o];
        acc += __uint_as_float(u.w << 16) * w2s[(k + 6) * 16 + o];
        acc += __uint_as_float(u.w & 0xffff0000u) * w2s[(k + 7) * 16 + o];
    }
    h2s[(size_t)node * 16 + o] = f2bf(acc * dinv[node]);
}

// ---------------- agg2: 4 lanes/node, uint2 (4 bf16 feats) per lane ----------------
__global__ __launch_bounds__(256) void k_agg2(const unsigned short* __restrict__ h2s,
                                              const int* __restrict__ rp,
                                              const int* __restrict__ csr,
                                              const float* __restrict__ dinv,
                                              const float* __restrict__ b2,
                                              float* __restrict__ out, int n) {
    int wid = (blockIdx.x * 256 + threadIdx.x) >> 6;
    int lane = threadIdx.x & 63;
    int slot = lane >> 2;
    int q = lane & 3;
    int node = wid * 16 + slot;
    bool valid = node < n;
    int nodec = valid ? node : n - 1;
    int start = rp[nodec];
    int deg = rp[nodec + 1] - start;
    int mx = deg;
#pragma unroll
    for (int off = 4; off < 64; off <<= 1) mx = max(mx, __shfl_xor(mx, off));
    uint2 us = *(const uint2*)(h2s + ((unsigned)nodec << 4) + q * 4);
    float a0 = bf2f((unsigned short)(us.x & 0xffff));
    float a1 = bf2f((unsigned short)(us.x >> 16));
    float a2 = bf2f((unsigned short)(us.y & 0xffff));
    float a3 = bf2f((unsigned short)(us.y >> 16));
    int clampi = deg > 0 ? deg - 1 : 0;
    int e = 0;
    for (; e + 2 <= mx; e += 2) {
        int s0 = csr[start + min(e, clampi)];
        int s1 = csr[start + min(e + 1, clampi)];
        uint2 u0 = *(const uint2*)(h2s + ((unsigned)s0 << 4) + q * 4);
        uint2 u1 = *(const uint2*)(h2s + ((unsigned)s1 << 4) + q * 4);
        if (e < deg) {
            a0 += bf2f((unsigned short)(u0.x & 0xffff));
            a1 += bf2f((unsigned short)(u0.x >> 16));
            a2 += bf2f((unsigned short)(u0.y & 0xffff));
            a3 += bf2f((unsigned short)(u0.y >> 16));
        }
        if (e + 1 < deg) {
            a0 += bf2f((unsigned short)(u1.x & 0xffff));
            a1 += bf2f((unsigned short)(u1.x >> 16));
            a2 += bf2f((unsigned short)(u1.y & 0xffff));
            a3 += bf2f((unsigned short)(u1.y >> 16));
        }
    }
    if (e < mx && e < deg) {
        int s = csr[start + e];
        uint2 u = *(const uint2*)(h2s + ((unsigned)s << 4) + q * 4);
        a0 += bf2f((unsigned short)(u.x & 0xffff));
        a1 += bf2f((unsigned short)(u.x >> 16));
        a2 += bf2f((unsigned short)(u.y & 0xffff));
        a3 += bf2f((unsigned short)(u.y >> 16));
    }
    if (valid) {
        float dv = dinv[node];
        float4 bb = *(const float4*)(b2 + q * 4);
        float4 o4 = make_float4(dv * a0 + bb.x, dv * a1 + bb.y,
                                dv * a2 + bb.z, dv * a3 + bb.w);
        *(float4*)(out + ((unsigned)node << 4) + q * 4) = o4;
    }
}

extern "C" void kernel_launch(void* const* d_in, const int* in_sizes, int n_in,
                              void* d_out, int out_size, void* d_ws, size_t ws_size,
                              hipStream_t stream) {
    const float* X  = (const float*)d_in[0];
    const int*   ei = (const int*)d_in[1];
    const float* W1 = (const float*)d_in[2];
    const float* b1 = (const float*)d_in[3];
    const float* W2 = (const float*)d_in[4];
    const float* b2 = (const float*)d_in[5];
    float* out = (float*)d_out;

    const int n = in_sizes[0] / N_FEAT_IN;   // 100000
    const int E = in_sizes[1] / 2;           // 1600000
    const int* src = ei;
    const int* dst = ei + E;

    char* ws = (char*)d_ws;
    size_t off = 0;
    auto alloc = [&](size_t bytes) -> char* {
        char* p = ws + off;
        off = (off + bytes + 255) & ~(size_t)255;
        return p;
    };
    float*          dinv    = (float*)alloc((size_t)n * 4);
    int*            row_ptr = (int*)alloc((size_t)(n + 1) * 4);
    int*            bbc     = (int*)alloc((size_t)NBUCK * NBINBLK * 4);  // 1 MB
    int*            btot    = (int*)alloc(NBUCK * 4);
    int*            bbase   = (int*)alloc((NBUCK + 1) * 4);
    int*            csr     = (int*)alloc((size_t)E * 4);
    int*            ebuf    = (int*)alloc((size_t)E * 4);                // 6.4 MB packed
    unsigned short* W1t     = (unsigned short*)alloc(128 * 256 * 2);     // 64 KB
    unsigned short* h1s     = (unsigned short*)alloc((size_t)n * 128 * 2);
    unsigned short* tbuf    = (unsigned short*)alloc((size_t)n * 128 * 2);
    unsigned short* h2s     = (unsigned short*)alloc((size_t)n * 16 * 2);
    (void)ws_size;

    const int NBK = (n + 127) / 128;         // 782 used buckets
    const int chunk = (E + NBINBLK - 1) / NBINBLK;

    k_bhist<<<NBINBLK, 256, 0, stream>>>(dst, bbc, E, chunk);
    k_bexscan<<<NBUCK, 256, 0, stream>>>(bbc, btot);
    k_bscan<<<1, NBUCK, 0, stream>>>(btot, bbase);
    k_bin2<<<NBINBLK, 256, 0, stream>>>(src, dst, bbc, bbase, ebuf, E, chunk);
    k_sortb<<<NBK, 256, 0, stream>>>(ebuf, bbase, row_ptr, dinv, csr, n, E);

    k_prep<<<128, 256, 0, stream>>>(W1, W1t);
    k_gemm1<<<(n + 63) / 64, 256, 0, stream>>>(X, W1t, dinv, h1s, n);
    k_agg1<<<(n / 2 + 3) / 4, 256, 0, stream>>>(h1s, row_ptr, csr, dinv, b1, tbuf, n);
    k_gemm2<<<((size_t)n * 16 + 255) / 256, 256, 0, stream>>>(tbuf, W2, dinv, h2s, n);
    k_agg2<<<(n + 63) / 64, 256, 0, stream>>>(h2s, row_ptr, csr, dinv, b2, out, n);
}

// Round 9
// 346.535 us; speedup vs baseline: 1.1099x; 1.0154x over previous
//
#include <hip/hip_runtime.h>
#include <hip/hip_bf16.h>

// SocialGNN: 2-layer GCN, N=100000 nodes, E=1600000 edges (+ self loops),
// feat 256 -> 128 (relu) -> 16.
//
// R9: gemm1 restructured around "W1 fits in LDS": the whole 64 KB bf16 weight
// is loaded into LDS once (single barrier), k-loop is barrier-free -- per lane
// 2 coalesced float4 X loads (A direct from global: R7 showed the A side was
// fine; it was the per-wave-redundant B stream that needed LDS), in-register
// cvt, 8 ds_read_b128 + 8 MFMA. W1t prepacked [kq][n][8] so the LDS fill is a
// flat memcpy and B reads are 2-way-bank only (free).
// History: R2 -- never funnel E atomics into <1K addresses. R4 -- bf16
// intermediates halve gather traffic; error attenuated by dinv~0.24 twice per
// layer. R5/R8 -- agg1 plateau ~74us broken to <64us by 2 nodes/wave. R7 --
// per-wave-redundant MFMA operand streams from global = 2x regression.
// R8 -- 2-barrier-per-kstep LDS gemm1 is stall-bound at 66us (MfmaUtil 3.6%,
// all pipes idle); [n][40] LDS pad has period-8 bank map (3M conflict cyc).

typedef __attribute__((ext_vector_type(8))) short short8;
typedef __attribute__((ext_vector_type(4))) float f32x4;

__device__ inline unsigned short f2bf(float f) {
    __hip_bfloat16 h = __float2bfloat16(f);
    return *(unsigned short*)&h;
}
__device__ inline float bf2f(unsigned short u) {
    unsigned int v = ((unsigned int)u) << 16;
    return *(float*)&v;
}

#define N_FEAT_IN 256
#define NBUCK 1024     // dst>>7; used buckets = ceil(n/128) = 782
#define NBINBLK 256    // partition blocks; bbc is [NBUCK][NBINBLK]

// ---------------- partition pass 1: per-(block,bucket) LDS histogram ----------------
__global__ __launch_bounds__(256) void k_bhist(const int* __restrict__ dst,
                                               int* __restrict__ bbc, int E, int chunk) {
    __shared__ int lcnt[NBUCK];
    for (int i = threadIdx.x; i < NBUCK; i += 256) lcnt[i] = 0;
    __syncthreads();
    int start = blockIdx.x * chunk;
    int end = min(start + chunk, E);
    for (int e = start + threadIdx.x; e < end; e += 256)
        atomicAdd(&lcnt[dst[e] >> 7], 1);
    __syncthreads();
    for (int i = threadIdx.x; i < NBUCK; i += 256)
        bbc[i * NBINBLK + blockIdx.x] = lcnt[i];
}

// ---- partition pass 2: per-bucket local exclusive scan across blocks + totals ----
__global__ __launch_bounds__(256) void k_bexscan(int* __restrict__ bbc,
                                                 int* __restrict__ btot) {
    __shared__ int ts[NBINBLK];
    int bucket = blockIdx.x;
    int t = threadIdx.x;
    int v = bbc[bucket * NBINBLK + t];
    ts[t] = v; __syncthreads();
    for (int off = 1; off < NBINBLK; off <<= 1) {
        int x = (t >= off) ? ts[t - off] : 0;
        __syncthreads();
        ts[t] += x;
        __syncthreads();
    }
    bbc[bucket * NBINBLK + t] = ts[t] - v;   // local exclusive (no base yet)
    if (t == NBINBLK - 1) btot[bucket] = ts[t];
}

// ---------------- bucket-total exclusive scan -> bucket bases ----------------
__global__ __launch_bounds__(1024) void k_bscan(const int* __restrict__ btot,
                                                int* __restrict__ bbase) {
    __shared__ int ts[NBUCK];
    int t = threadIdx.x;
    int v = btot[t];
    ts[t] = v; __syncthreads();
    for (int off = 1; off < NBUCK; off <<= 1) {
        int x = (t >= off) ? ts[t - off] : 0;
        __syncthreads();
        ts[t] += x;
        __syncthreads();
    }
    bbase[t] = ts[t] - v;  // exclusive
}

// ---------------- partition pass 3: binned write (24-bit packed) ----------------
// packed edge: bits 0-16 src (n<2^17), bits 17-23 dst&127.
__global__ __launch_bounds__(256) void k_bin2(const int* __restrict__ src,
                                              const int* __restrict__ dst,
                                              const int* __restrict__ bbc,
                                              const int* __restrict__ bbase,
                                              int* __restrict__ ebuf, int E, int chunk) {
    __shared__ int lcur[NBUCK];
    for (int i = threadIdx.x; i < NBUCK; i += 256)
        lcur[i] = bbc[i * NBINBLK + blockIdx.x] + bbase[i];
    __syncthreads();
    int start = blockIdx.x * chunk;
    int end = min(start + chunk, E);
    for (int e = start + threadIdx.x; e < end; e += 256) {
        int s = src[e], d = dst[e];
        int pos = atomicAdd(&lcur[d >> 7], 1);  // LDS atomic
        ebuf[pos] = s | ((d & 127) << 17);
    }
}

// ---- per-bucket counting sort: ebuf window -> csr; also row_ptr, dinv ----
__global__ __launch_bounds__(256) void k_sortb(const int* __restrict__ ebuf,
                                               const int* __restrict__ bbase,
                                               int* __restrict__ row_ptr,
                                               float* __restrict__ dinv,
                                               int* __restrict__ csr, int n, int E) {
    __shared__ int lcnt[128];
    __shared__ int lcur[128];
    int b = blockIdx.x;
    int node0 = b << 7;
    int nodes = min(128, n - node0);
    int t = threadIdx.x;
    int s_start = bbase[b];
    int s_end = bbase[b + 1];
    if (t < 128) lcnt[t] = 0;
    __syncthreads();
    for (int e = s_start + t; e < s_end; e += 256)
        atomicAdd(&lcnt[(ebuf[e] >> 17) & 127], 1);
    __syncthreads();
    int deg = (t < 128) ? lcnt[t] : 0;
    if (t < 128) lcur[t] = deg;
    __syncthreads();
    for (int off = 1; off < 128; off <<= 1) {
        int x = 0;
        if (t < 128 && t >= off) x = lcur[t - off];
        __syncthreads();
        if (t < 128) lcur[t] += x;
        __syncthreads();
    }
    if (t < 128) {
        int excl = s_start + lcur[t] - deg;
        if (t < nodes) {
            row_ptr[node0 + t] = excl;
            dinv[node0 + t] = rsqrtf((float)deg + 1.0f);  // +1 self-loop
        }
        lcur[t] = excl;  // write cursor
    }
    if (b == 0 && t == 0) row_ptr[n] = E;
    __syncthreads();
    for (int e = s_start + t; e < s_end; e += 256) {
        int p = ebuf[e];
        int pos = atomicAdd(&lcur[(p >> 17) & 127], 1);  // LDS atomic
        csr[pos] = p & 0x1FFFF;
    }
}

// ------ W1 [256][128] f32 -> W1t packed [kq 0..31][n 0..127][j 0..7] bf16 ------
// element (n, k=kq*8+j) lives at W1t[kq*1024 + n*8 + j].
__global__ void k_prep(const float* __restrict__ W1, unsigned short* __restrict__ W1t) {
    int nn = blockIdx.x;          // 0..127
    int k = threadIdx.x;          // 0..255
    int kq = k >> 3, j = k & 7;
    W1t[kq * 1024 + nn * 8 + j] = f2bf(W1[k * 128 + nn]);
}

// ---------------- GEMM1 (MFMA, resident-B): X[M,256]f32 @ W1 -> h1s bf16, *dinv -----
// W1 (64 KB bf16, kq-major) loaded to LDS once; k-loop barrier-free: per lane
// 2 coalesced float4 A loads from X + cvt + 8 ds_read_b128 + 8 MFMA.
__global__ __launch_bounds__(256) void k_gemm1(const float* __restrict__ X,
                                               const unsigned short* __restrict__ W1t,
                                               const float* __restrict__ dinv,
                                               unsigned short* __restrict__ h1s, int M) {
    __shared__ unsigned short Bs[32768];   // 64 KB, [kq][n][8]
    const int tid = threadIdx.x;
    const int wv = tid >> 6;
    const int lane = tid & 63;
    const int hq = lane >> 4;       // quad 0..3
    const int l15 = lane & 15;
    const int block_row = blockIdx.x * 64;

    // flat 64 KB memcpy global->LDS (uint4 = 16 B per thread per iter)
#pragma unroll
    for (int i = 0; i < 16; ++i)
        ((uint4*)Bs)[tid + i * 256] = ((const uint4*)W1t)[tid + i * 256];
    __syncthreads();

    int arow = block_row + wv * 16 + l15;
    if (arow >= M) arow = M - 1;                       // clamp; stores masked
    const float* xp = X + (size_t)arow * 256 + hq * 8;

    f32x4 acc[8];
#pragma unroll
    for (int c = 0; c < 8; ++c) acc[c] = (f32x4){0.f, 0.f, 0.f, 0.f};

#pragma unroll
    for (int ks = 0; ks < 8; ++ks) {                   // k0 = 32*ks
        float4 a0 = *(const float4*)(xp + 32 * ks);
        float4 a1 = *(const float4*)(xp + 32 * ks + 4);
        short8 a;
        a[0] = (short)f2bf(a0.x); a[1] = (short)f2bf(a0.y);
        a[2] = (short)f2bf(a0.z); a[3] = (short)f2bf(a0.w);
        a[4] = (short)f2bf(a1.x); a[5] = (short)f2bf(a1.y);
        a[6] = (short)f2bf(a1.z); a[7] = (short)f2bf(a1.w);
        const unsigned short* bp = Bs + (ks * 4 + hq) * 1024 + l15 * 8;
#pragma unroll
        for (int c = 0; c < 8; ++c) {
            short8 b = *(const short8*)(bp + c * 128);
            acc[c] = __builtin_amdgcn_mfma_f32_16x16x32_bf16(a, b, acc[c], 0, 0, 0);
        }
    }
    // D: row = 16wv + hq*4 + r, col = c*16 + l15
#pragma unroll
    for (int r = 0; r < 4; ++r) {
        int row = block_row + 16 * wv + hq * 4 + r;
        if (row < M) {
            float dv = dinv[row];
#pragma unroll
            for (int c = 0; c < 8; ++c) {
                int col = c * 16 + l15;
                h1s[(size_t)row * 128 + col] = f2bf(acc[c][r] * dv);
            }
        }
    }
}

// ---------------- agg1: TWO nodes per wave (32 lanes x uint2 = 256B row) -------------
__global__ __launch_bounds__(256) void k_agg1(const unsigned short* __restrict__ h1s,
                                              const int* __restrict__ rp,
                                              const int* __restrict__ csr,
                                              const float* __restrict__ dinv,
                                              const float* __restrict__ b1,
                                              unsigned short* __restrict__ tbuf, int n) {
    int pr = (blockIdx.x * 256 + threadIdx.x) >> 6;  // wave id = node pair
    int lane = threadIdx.x & 63;
    int half = lane >> 5;
    int l = lane & 31;
    int node = pr * 2 + half;
    if (node >= n) return;
    const uint2* hv = (const uint2*)h1s;  // 32 uint2 per 128-feat row
    uint2 us = hv[((unsigned)node << 5) + l];  // self (already *dinv)
    float a0 = bf2f((unsigned short)(us.x & 0xffff));
    float a1 = bf2f((unsigned short)(us.x >> 16));
    float a2 = bf2f((unsigned short)(us.y & 0xffff));
    float a3 = bf2f((unsigned short)(us.y >> 16));
    int start = rp[node], end = rp[node + 1];
    int e = start;
    for (; e + 4 <= end; e += 4) {
        uint2 u0 = hv[((unsigned)csr[e + 0] << 5) + l];
        uint2 u1 = hv[((unsigned)csr[e + 1] << 5) + l];
        uint2 u2 = hv[((unsigned)csr[e + 2] << 5) + l];
        uint2 u3 = hv[((unsigned)csr[e + 3] << 5) + l];
        a0 += (bf2f((unsigned short)(u0.x & 0xffff)) + bf2f((unsigned short)(u1.x & 0xffff))) +
              (bf2f((unsigned short)(u2.x & 0xffff)) + bf2f((unsigned short)(u3.x & 0xffff)));
        a1 += (bf2f((unsigned short)(u0.x >> 16)) + bf2f((unsigned short)(u1.x >> 16))) +
              (bf2f((unsigned short)(u2.x >> 16)) + bf2f((unsigned short)(u3.x >> 16)));
        a2 += (bf2f((unsigned short)(u0.y & 0xffff)) + bf2f((unsigned short)(u1.y & 0xffff))) +
              (bf2f((unsigned short)(u2.y & 0xffff)) + bf2f((unsigned short)(u3.y & 0xffff)));
        a3 += (bf2f((unsigned short)(u0.y >> 16)) + bf2f((unsigned short)(u1.y >> 16))) +
              (bf2f((unsigned short)(u2.y >> 16)) + bf2f((unsigned short)(u3.y >> 16)));
    }
    for (; e < end; ++e) {
        uint2 u = hv[((unsigned)csr[e] << 5) + l];
        a0 += bf2f((unsigned short)(u.x & 0xffff));
        a1 += bf2f((unsigned short)(u.x >> 16));
        a2 += bf2f((unsigned short)(u.y & 0xffff));
        a3 += bf2f((unsigned short)(u.y >> 16));
    }
    float dv = dinv[node];
    float4 bb = ((const float4*)b1)[l];
    float t0 = fmaxf(dv * a0 + bb.x, 0.0f);
    float t1 = fmaxf(dv * a1 + bb.y, 0.0f);
    float t2 = fmaxf(dv * a2 + bb.z, 0.0f);
    float t3 = fmaxf(dv * a3 + bb.w, 0.0f);
    uint2 packed;
    packed.x = (unsigned int)f2bf(t0) | ((unsigned int)f2bf(t1) << 16);
    packed.y = (unsigned int)f2bf(t2) | ((unsigned int)f2bf(t3) << 16);
    ((uint2*)tbuf)[((unsigned)node << 5) + l] = packed;
}

// ---------------- GEMM2: tbuf[n,128]bf16 @ W2[128,16]f32 -> h2s bf16, *dinv ----------
__global__ __launch_bounds__(256) void k_gemm2(const unsigned short* __restrict__ tbuf,
                                               const float* __restrict__ W2,
                                               const float* __restrict__ dinv,
                                               unsigned short* __restrict__ h2s, int n) {
    __shared__ float w2s[128 * 16];
    for (int i = threadIdx.x; i < 2048; i += 256) w2s[i] = W2[i];
    __syncthreads();
    int gid = blockIdx.x * 256 + threadIdx.x;
    int node = gid >> 4;
    int o = gid & 15;
    if (node >= n) return;
    const uint4* tv = (const uint4*)(tbuf + (size_t)node * 128);  // 16 x uint4
    float acc = 0.0f;
#pragma unroll
    for (int i = 0; i < 16; ++i) {
        uint4 u = tv[i];
        int k = i * 8;
        acc += __uint_as_float(u.x << 16) * w2s[(k + 0) * 16 + o];
        acc += __uint_as_float(u.x & 0xffff0000u) * w2s[(k + 1) * 16 + o];
        acc += __uint_as_float(u.y << 16) * w2s[(k + 2) * 16 + o];
        acc += __uint_as_float(u.y & 0xffff0000u) * w2s[(k + 3) * 16 + o];
        acc += __uint_as_float(u.z << 16) * w2s[(k + 4) * 16 + o];
        acc += __uint_as_float(u.z & 0xffff0000u) * w2s[(k + 5) * 16 + o];
        acc += __uint_as_float(u.w << 16) * w2s[(k + 6) * 16 + o];
        acc += __uint_as_float(u.w & 0xffff0000u) * w2s[(k + 7) * 16 + o];
    }
    h2s[(size_t)node * 16 + o] = f2bf(acc * dinv[node]);
}

// ---------------- agg2: 4 lanes/node, uint2 (4 bf16 feats) per lane ----------------
__global__ __launch_bounds__(256) void k_agg2(const unsigned short* __restrict__ h2s,
                                              const int* __restrict__ rp,
                                              const int* __restrict__ csr,
                                              const float* __restrict__ dinv,
                                              const float* __restrict__ b2,
                                              float* __restrict__ out, int n) {
    int wid = (blockIdx.x * 256 + threadIdx.x) >> 6;
    int lane = threadIdx.x & 63;
    int slot = lane >> 2;
    int q = lane & 3;
    int node = wid * 16 + slot;
    bool valid = node < n;
    int nodec = valid ? node : n - 1;
    int start = rp[nodec];
    int deg = rp[nodec + 1] - start;
    int mx = deg;
#pragma unroll
    for (int off = 4; off < 64; off <<= 1) mx = max(mx, __shfl_xor(mx, off));
    uint2 us = *(const uint2*)(h2s + ((unsigned)nodec << 4) + q * 4);
    float a0 = bf2f((unsigned short)(us.x & 0xffff));
    float a1 = bf2f((unsigned short)(us.x >> 16));
    float a2 = bf2f((unsigned short)(us.y & 0xffff));
    float a3 = bf2f((unsigned short)(us.y >> 16));
    int clampi = deg > 0 ? deg - 1 : 0;
    int e = 0;
    for (; e + 2 <= mx; e += 2) {
        int s0 = csr[start + min(e, clampi)];
        int s1 = csr[start + min(e + 1, clampi)];
        uint2 u0 = *(const uint2*)(h2s + ((unsigned)s0 << 4) + q * 4);
        uint2 u1 = *(const uint2*)(h2s + ((unsigned)s1 << 4) + q * 4);
        if (e < deg) {
            a0 += bf2f((unsigned short)(u0.x & 0xffff));
            a1 += bf2f((unsigned short)(u0.x >> 16));
            a2 += bf2f((unsigned short)(u0.y & 0xffff));
            a3 += bf2f((unsigned short)(u0.y >> 16));
        }
        if (e + 1 < deg) {
            a0 += bf2f((unsigned short)(u1.x & 0xffff));
            a1 += bf2f((unsigned short)(u1.x >> 16));
            a2 += bf2f((unsigned short)(u1.y & 0xffff));
            a3 += bf2f((unsigned short)(u1.y >> 16));
        }
    }
    if (e < mx && e < deg) {
        int s = csr[start + e];
        uint2 u = *(const uint2*)(h2s + ((unsigned)s << 4) + q * 4);
        a0 += bf2f((unsigned short)(u.x & 0xffff));
        a1 += bf2f((unsigned short)(u.x >> 16));
        a2 += bf2f((unsigned short)(u.y & 0xffff));
        a3 += bf2f((unsigned short)(u.y >> 16));
    }
    if (valid) {
        float dv = dinv[node];
        float4 bb = *(const float4*)(b2 + q * 4);
        float4 o4 = make_float4(dv * a0 + bb.x, dv * a1 + bb.y,
                                dv * a2 + bb.z, dv * a3 + bb.w);
        *(float4*)(out + ((unsigned)node << 4) + q * 4) = o4;
    }
}

extern "C" void kernel_launch(void* const* d_in, const int* in_sizes, int n_in,
                              void* d_out, int out_size, void* d_ws, size_t ws_size,
                              hipStream_t stream) {
    const float* X  = (const float*)d_in[0];
    const int*   ei = (const int*)d_in[1];
    const float* W1 = (const float*)d_in[2];
    const float* b1 = (const float*)d_in[3];
    const float* W2 = (const float*)d_in[4];
    const float* b2 = (const float*)d_in[5];
    float* out = (float*)d_out;

    const int n = in_sizes[0] / N_FEAT_IN;   // 100000
    const int E = in_sizes[1] / 2;           // 1600000
    const int* src = ei;
    const int* dst = ei + E;

    char* ws = (char*)d_ws;
    size_t off = 0;
    auto alloc = [&](size_t bytes) -> char* {
        char* p = ws + off;
        off = (off + bytes + 255) & ~(size_t)255;
        return p;
    };
    float*          dinv    = (float*)alloc((size_t)n * 4);
    int*            row_ptr = (int*)alloc((size_t)(n + 1) * 4);
    int*            bbc     = (int*)alloc((size_t)NBUCK * NBINBLK * 4);  // 1 MB
    int*            btot    = (int*)alloc(NBUCK * 4);
    int*            bbase   = (int*)alloc((NBUCK + 1) * 4);
    int*            csr     = (int*)alloc((size_t)E * 4);
    int*            ebuf    = (int*)alloc((size_t)E * 4);                // 6.4 MB packed
    unsigned short* W1t     = (unsigned short*)alloc(128 * 256 * 2);     // 64 KB packed
    unsigned short* h1s     = (unsigned short*)alloc((size_t)n * 128 * 2);
    unsigned short* tbuf    = (unsigned short*)alloc((size_t)n * 128 * 2);
    unsigned short* h2s     = (unsigned short*)alloc((size_t)n * 16 * 2);
    (void)ws_size;

    const int NBK = (n + 127) / 128;         // 782 used buckets
    const int chunk = (E + NBINBLK - 1) / NBINBLK;

    k_bhist<<<NBINBLK, 256, 0, stream>>>(dst, bbc, E, chunk);
    k_bexscan<<<NBUCK, 256, 0, stream>>>(bbc, btot);
    k_bscan<<<1, NBUCK, 0, stream>>>(btot, bbase);
    k_bin2<<<NBINBLK, 256, 0, stream>>>(src, dst, bbc, bbase, ebuf, E, chunk);
    k_sortb<<<NBK, 256, 0, stream>>>(ebuf, bbase, row_ptr, dinv, csr, n, E);

    k_prep<<<128, 256, 0, stream>>>(W1, W1t);
    k_gemm1<<<(n + 63) / 64, 256, 0, stream>>>(X, W1t, dinv, h1s, n);
    k_agg1<<<(n / 2 + 3) / 4, 256, 0, stream>>>(h1s, row_ptr, csr, dinv, b1, tbuf, n);
    k_gemm2<<<((size_t)n * 16 + 255) / 256, 256, 0, stream>>>(tbuf, W2, dinv, h2s, n);
    k_agg2<<<(n + 63) / 64, 256, 0, stream>>>(h2s, row_ptr, csr, dinv, b2, out, n);
}